// Round 2
// baseline (18.369 us; speedup 1.0000x reference)
//
#include <hip/hip_runtime.h>

// Retrace loss via backward linear recurrence (validated R1, absmax 0.0):
//   c[t] = gamma*exp(max(tlp-olp,0));  A[t] = rewards - tq_traj
//   R[t] = A[t] + c[t]*R[t+1];  Wsum[t] = 1 + c[t]*Wsum[t+1]
//   retrace[t] = R[t] + tq_curr[t]*Wsum[t];  loss = mean((q-retrace)^2)
//
// R2: spread the scan over all 256 CUs. Grid = 16 colTiles x 16 rowGroups.
// K1 computes per-(group,col) segment composition (R,W,C) -> ws.
// K2 folds later-group carries (L2-hot), replays its 16-row slab,
// reduces, and the last block (atomic ticket) writes the mean.

constexpr int   T     = 256;
constexpr int   B     = 1024;
constexpr float GAMMA = 0.95f;

constexpr int NCT  = 16;          // column tiles (64 cols each)
constexpr int NG   = 16;          // row groups
constexpr int GR   = T / NG;      // 16 rows per group
constexpr int NBLK = NCT * NG;    // 256 blocks

__global__ __launch_bounds__(1024) void retrace_partials(
    const float* __restrict__ tq_traj,
    const float* __restrict__ rewards,
    const float* __restrict__ olp,
    const float* __restrict__ tlp,
    float* __restrict__ wsR, float* __restrict__ wsW, float* __restrict__ wsC,
    unsigned* __restrict__ ticket)
{
    const int lane = threadIdx.x & 63;   // col within tile
    const int w    = threadIdx.x >> 6;   // row within group (0..15)
    const int ct   = blockIdx.x & (NCT - 1);
    const int g    = blockIdx.x >> 4;
    const int col  = ct * 64 + lane;
    const int row  = g * GR + w;
    const int idx  = row * B + col;

    const float lw = fmaxf(tlp[idx] - olp[idx], 0.f);
    const float c  = GAMMA * __expf(lw);
    const float A  = rewards[idx] - tq_traj[idx];

    __shared__ float sA[GR][64], sC[GR][64];
    sA[w][lane] = A;
    sC[w][lane] = c;
    __syncthreads();

    if (w == 0) {
        float R = 0.f, W = 0.f, C = 1.f;
        #pragma unroll
        for (int r = GR - 1; r >= 0; --r) {
            const float cc = sC[r][lane];
            R = fmaf(cc, R, sA[r][lane]);
            W = fmaf(cc, W, 1.f);
            C *= cc;
        }
        wsR[g * B + col] = R;
        wsW[g * B + col] = W;
        wsC[g * B + col] = C;
    }
    // re-arm the completion ticket for kernel 2 (stream-ordered => safe)
    if (blockIdx.x == 0 && threadIdx.x == 0) *ticket = 0u;
}

__global__ __launch_bounds__(1024) void retrace_finish(
    const float* __restrict__ q,
    const float* __restrict__ tq_traj,
    const float* __restrict__ tq_curr,
    const float* __restrict__ rewards,
    const float* __restrict__ olp,
    const float* __restrict__ tlp,
    const float* __restrict__ wsR,
    const float* __restrict__ wsW,
    const float* __restrict__ wsC,
    float* __restrict__ partials,
    unsigned* __restrict__ ticket,
    float* __restrict__ out)
{
    const int lane = threadIdx.x & 63;
    const int w    = threadIdx.x >> 6;
    const int ct   = blockIdx.x & (NCT - 1);
    const int g    = blockIdx.x >> 4;
    const int col  = ct * 64 + lane;
    const int row  = g * GR + w;
    const int idx  = row * B + col;

    // incoming carry from all later groups (L2-resident workspace)
    float Rc = 0.f, Wc = 0.f;
    for (int gg = NG - 1; gg > g; --gg) {
        const float Cg = wsC[gg * B + col];
        Rc = fmaf(Cg, Rc, wsR[gg * B + col]);
        Wc = fmaf(Cg, Wc, wsW[gg * B + col]);
    }

    const float lw = fmaxf(tlp[idx] - olp[idx], 0.f);
    const float c  = GAMMA * __expf(lw);
    const float A  = rewards[idx] - tq_traj[idx];

    __shared__ float sA[GR][64], sC[GR][64];
    sA[w][lane] = A;
    sC[w][lane] = c;
    __syncthreads();

    // fold rows below mine within the group, seeded with the group carry
    float R = Rc, W = Wc;
    for (int r = GR - 1; r > w; --r) {
        const float cc = sC[r][lane];
        R = fmaf(cc, R, sA[r][lane]);
        W = fmaf(cc, W, 1.f);
    }
    // my row
    R = fmaf(c, R, A);
    W = fmaf(c, W, 1.f);

    const float retrace = fmaf(tq_curr[idx], W, R);
    const float d = q[idx] - retrace;
    float acc = d * d;

    // wave reduction
    #pragma unroll
    for (int off = 32; off > 0; off >>= 1)
        acc += __shfl_down(acc, off, 64);

    __shared__ float sw[GR];
    if (lane == 0) sw[w] = acc;
    __syncthreads();

    __shared__ bool last;
    if (threadIdx.x == 0) {
        float t = 0.f;
        #pragma unroll
        for (int i = 0; i < GR; ++i) t += sw[i];
        partials[blockIdx.x] = t;
        __threadfence();
        last = (atomicAdd(ticket, 1u) == (unsigned)(NBLK - 1));
    }
    __syncthreads();

    if (last && w == 0) {
        __threadfence();  // acquire: make other blocks' partials visible
        float t = partials[lane] + partials[lane + 64]
                + partials[lane + 128] + partials[lane + 192];
        #pragma unroll
        for (int off = 32; off > 0; off >>= 1)
            t += __shfl_down(t, off, 64);
        if (lane == 0) out[0] = t / (float)(T * B);
    }
}

extern "C" void kernel_launch(void* const* d_in, const int* in_sizes, int n_in,
                              void* d_out, int out_size, void* d_ws, size_t ws_size,
                              hipStream_t stream)
{
    const float* q       = (const float*)d_in[0];
    const float* tq_traj = (const float*)d_in[1];
    const float* tq_curr = (const float*)d_in[2];
    const float* rewards = (const float*)d_in[3];
    const float* olp     = (const float*)d_in[4];
    const float* tlp     = (const float*)d_in[5];

    float* wsR      = (float*)d_ws;
    float* wsW      = wsR + NG * B;
    float* wsC      = wsW + NG * B;
    float* partials = wsC + NG * B;
    unsigned* ticket = (unsigned*)(partials + NBLK);
    float* out      = (float*)d_out;

    retrace_partials<<<NBLK, 1024, 0, stream>>>(
        tq_traj, rewards, olp, tlp, wsR, wsW, wsC, ticket);
    retrace_finish<<<NBLK, 1024, 0, stream>>>(
        q, tq_traj, tq_curr, rewards, olp, tlp,
        wsR, wsW, wsC, partials, ticket, out);
}

// Round 3
// 17.046 us; speedup vs baseline: 1.0776x; 1.0776x over previous
//
#include <hip/hip_runtime.h>

// Retrace loss via backward linear recurrence (validated R1, absmax 0.0):
//   c[t] = gamma*exp(max(tlp-olp,0));  A[t] = rewards - tq_traj
//   R[t] = A[t] + c[t]*R[t+1];  Wsum[t] = 1 + c[t]*Wsum[t+1]
//   retrace[t] = R[t] + tq_curr[t]*Wsum[t];  loss = mean((q-retrace)^2)
//
// R3: single-read structure. For row t in group g (16 rows/group):
//   R_full[t] = R_local[t] + Csuf[t]*Rc ;  W_full[t] = W_local[t] + Csuf[t]*Wc
//   diff[t]   = a0[t] - a1[t]*Rc - a2[t]*Wc
//     a0 = q - R_local - tq_curr*W_local ; a1 = Csuf ; a2 = tq_curr*Csuf
// => sum_t diff^2 over a group needs only 6 per-column moments + the
//    (Rg,Wg,Cg) carry summary. K1 computes those (inputs read ONCE).
// K2 (1 block) folds carries per column over 16 groups and reduces.

constexpr int   T     = 256;
constexpr int   B     = 1024;
constexpr float GAMMA = 0.95f;

constexpr int NCT  = 16;        // column tiles (64 cols)
constexpr int NG   = 16;        // row groups
constexpr int GR   = T / NG;    // 16 rows per group
constexpr int NBLK = NCT * NG;  // 256 blocks

// ws layout: 9 planes of [NG][B] floats:
//   0..5 = S00,S01,S02,S11,S12,S22 ; 6=Rg ; 7=Wg ; 8=Cg
__device__ __forceinline__ int wsi(int plane, int g, int col) {
    return (plane * NG + g) * B + col;
}

__global__ __launch_bounds__(1024) void retrace_moments(
    const float* __restrict__ q,
    const float* __restrict__ tq_traj,
    const float* __restrict__ tq_curr,
    const float* __restrict__ rewards,
    const float* __restrict__ olp,
    const float* __restrict__ tlp,
    float* __restrict__ ws)
{
    const int lane = threadIdx.x & 63;
    const int w    = threadIdx.x >> 6;        // row within group
    const int ct   = blockIdx.x & (NCT - 1);
    const int g    = blockIdx.x >> 4;
    const int col  = ct * 64 + lane;
    const int idx  = (g * GR + w) * B + col;

    const float lw = fmaxf(tlp[idx] - olp[idx], 0.f);
    const float c  = GAMMA * __expf(lw);
    const float A  = rewards[idx] - tq_traj[idx];
    const float qv = q[idx];
    const float tc = tq_curr[idx];

    __shared__ float sC[GR][64], sA[GR][64];
    sC[w][lane] = c;
    sA[w][lane] = A;
    __syncthreads();

    // per-thread suffix fold over rows w..15 (includes own row)
    float R = 0.f, W = 0.f, C = 1.f;
    for (int r = GR - 1; r >= w; --r) {            // wave-uniform trip count
        const float cc = sC[r][lane];
        R = fmaf(cc, R, sA[r][lane]);
        W = fmaf(cc, W, 1.f);
        C *= cc;
    }

    const float a0 = qv - R - tc * W;
    const float a1 = C;
    const float a2 = tc * C;

    __shared__ float sm[6][GR][64];
    sm[0][w][lane] = a0 * a0;
    sm[1][w][lane] = a0 * a1;
    sm[2][w][lane] = a0 * a2;
    sm[3][w][lane] = a1 * a1;
    sm[4][w][lane] = a1 * a2;
    sm[5][w][lane] = a2 * a2;

    if (w == 0) {   // group summary (R_local/W_local/Csuf at the group head)
        ws[wsi(6, g, col)] = R;
        ws[wsi(7, g, col)] = W;
        ws[wsi(8, g, col)] = C;
    }
    __syncthreads();

    if (w < 6) {    // waves 0..5 each reduce one moment over the 16 rows
        float s = 0.f;
        #pragma unroll
        for (int r = 0; r < GR; ++r) s += sm[w][r][lane];
        ws[wsi(w, g, col)] = s;
    }
}

__global__ __launch_bounds__(1024) void retrace_combine(
    const float* __restrict__ ws,
    float* __restrict__ out)
{
    const int col = threadIdx.x;   // 1024 columns, coalesced
    float Rc = 0.f, Wc = 0.f, loss = 0.f;

    #pragma unroll
    for (int g = NG - 1; g >= 0; --g) {
        const float S00 = ws[wsi(0, g, col)];
        const float S01 = ws[wsi(1, g, col)];
        const float S02 = ws[wsi(2, g, col)];
        const float S11 = ws[wsi(3, g, col)];
        const float S12 = ws[wsi(4, g, col)];
        const float S22 = ws[wsi(5, g, col)];
        const float Rg  = ws[wsi(6, g, col)];
        const float Wg  = ws[wsi(7, g, col)];
        const float Cg  = ws[wsi(8, g, col)];

        loss += S00 - 2.f * Rc * S01 - 2.f * Wc * S02
              + Rc * Rc * S11 + 2.f * Rc * Wc * S12 + Wc * Wc * S22;

        Rc = fmaf(Cg, Rc, Rg);   // prepend group g to the carry
        Wc = fmaf(Cg, Wc, Wg);
    }

    #pragma unroll
    for (int off = 32; off > 0; off >>= 1)
        loss += __shfl_down(loss, off, 64);

    __shared__ float sw[16];
    const int lane = threadIdx.x & 63, wv = threadIdx.x >> 6;
    if (lane == 0) sw[wv] = loss;
    __syncthreads();
    if (threadIdx.x == 0) {
        float t = 0.f;
        #pragma unroll
        for (int i = 0; i < 16; ++i) t += sw[i];
        out[0] = t / (float)(T * B);
    }
}

extern "C" void kernel_launch(void* const* d_in, const int* in_sizes, int n_in,
                              void* d_out, int out_size, void* d_ws, size_t ws_size,
                              hipStream_t stream)
{
    const float* q       = (const float*)d_in[0];
    const float* tq_traj = (const float*)d_in[1];
    const float* tq_curr = (const float*)d_in[2];
    const float* rewards = (const float*)d_in[3];
    const float* olp     = (const float*)d_in[4];
    const float* tlp     = (const float*)d_in[5];

    float* ws  = (float*)d_ws;     // 9 * NG * B floats = 576 KB
    float* out = (float*)d_out;

    retrace_moments<<<NBLK, 1024, 0, stream>>>(
        q, tq_traj, tq_curr, rewards, olp, tlp, ws);
    retrace_combine<<<1, 1024, 0, stream>>>(ws, out);
}

// Round 4
// 10.954 us; speedup vs baseline: 1.6770x; 1.5561x over previous
//
#include <hip/hip_runtime.h>

// Retrace loss via backward linear recurrence (validated R1, absmax 0.0):
//   c[t] = gamma*exp(max(tlp-olp,0));  A[t] = rewards - tq_traj
//   R[t] = A[t] + c[t]*R[t+1];  Wsum[t] = 1 + c[t]*Wsum[t+1]
//   retrace[t] = R[t] + tq_curr[t]*Wsum[t];  loss = mean((q-retrace)^2)
//
// R4: no cross-block carries (cross-XCD handoff proved expensive in R2/R3),
// but 4x the CUs of R1: 64 blocks x 16 columns, full T per block.
// In-block: 64 segments x 4 rows; log-depth (6-step) suffix scan of
// (R,W,C) segment summaries in ping-pong LDS; replay from registers.

constexpr int   T     = 256;
constexpr int   B     = 1024;
constexpr float GAMMA = 0.95f;

constexpr int CPB  = 16;          // columns per block
constexpr int NBLK = B / CPB;     // 64 blocks
constexpr int RPT  = 4;           // rows per thread
constexpr int NSEG = T / RPT;     // 64 segments
// block = NSEG * CPB = 1024 threads ; tid = seg*CPB + col

__global__ __launch_bounds__(NSEG * CPB) void retrace_main(
    const float* __restrict__ q,
    const float* __restrict__ tq_traj,
    const float* __restrict__ tq_curr,
    const float* __restrict__ rewards,
    const float* __restrict__ olp,
    const float* __restrict__ tlp,
    float* __restrict__ partials)
{
    const int col  = threadIdx.x & (CPB - 1);
    const int seg  = threadIdx.x >> 4;            // 0..63
    const int gcol = blockIdx.x * CPB + col;
    const int r0   = seg * RPT;

    // ---- phase 1: load 4 rows, local backward fold ----
    float cb[RPT], Ab[RPT], qb[RPT], tb[RPT];
    float R = 0.f, W = 0.f, C = 1.f;
    #pragma unroll
    for (int k = RPT - 1; k >= 0; --k) {
        const int idx = (r0 + k) * B + gcol;
        const float lw = fmaxf(tlp[idx] - olp[idx], 0.f);
        const float c  = GAMMA * __expf(lw);
        const float A  = rewards[idx] - tq_traj[idx];
        cb[k] = c;  Ab[k] = A;
        qb[k] = q[idx];  tb[k] = tq_curr[idx];
        R = fmaf(c, R, A);
        W = fmaf(c, W, 1.f);
        C *= c;
    }

    // ---- phase 2: log-depth suffix scan over 64 segments (ping-pong) ----
    __shared__ float sR[2][NSEG][CPB + 1];
    __shared__ float sW[2][NSEG][CPB + 1];
    __shared__ float sC[2][NSEG][CPB + 1];

    int p = 0;
    sR[0][seg][col] = R;
    sW[0][seg][col] = W;
    sC[0][seg][col] = C;
    __syncthreads();

    #pragma unroll
    for (int d = 1; d < NSEG; d <<= 1) {
        float r = sR[p][seg][col];
        float w = sW[p][seg][col];
        float c = sC[p][seg][col];
        if (seg + d < NSEG) {
            r = fmaf(c, sR[p][seg + d][col], r);
            w = fmaf(c, sW[p][seg + d][col], w);
            c = c * sC[p][seg + d][col];
        }
        sR[p ^ 1][seg][col] = r;
        sW[p ^ 1][seg][col] = w;
        sC[p ^ 1][seg][col] = c;
        __syncthreads();
        p ^= 1;
    }

    // exclusive suffix carry = inclusive suffix of seg+1
    float Rc = 0.f, Wc = 0.f;
    if (seg + 1 < NSEG) {
        Rc = sR[p][seg + 1][col];
        Wc = sW[p][seg + 1][col];
    }

    // ---- phase 3: replay 4 rows from registers ----
    float acc = 0.f;
    #pragma unroll
    for (int k = RPT - 1; k >= 0; --k) {
        Rc = fmaf(cb[k], Rc, Ab[k]);
        Wc = fmaf(cb[k], Wc, 1.f);
        const float retrace = fmaf(tb[k], Wc, Rc);
        const float d = qb[k] - retrace;
        acc = fmaf(d, d, acc);
    }

    // ---- block reduction (deterministic) ----
    #pragma unroll
    for (int off = 32; off > 0; off >>= 1)
        acc += __shfl_down(acc, off, 64);

    __shared__ float sw[16];
    const int lane = threadIdx.x & 63, wv = threadIdx.x >> 6;
    if (lane == 0) sw[wv] = acc;
    __syncthreads();
    if (threadIdx.x == 0) {
        float t = 0.f;
        #pragma unroll
        for (int i = 0; i < 16; ++i) t += sw[i];
        partials[blockIdx.x] = t;
    }
}

__global__ void retrace_final(const float* __restrict__ partials,
                              float* __restrict__ out)
{
    float v = (threadIdx.x < NBLK) ? partials[threadIdx.x] : 0.f;
    #pragma unroll
    for (int off = 32; off > 0; off >>= 1)
        v += __shfl_down(v, off, 64);
    if (threadIdx.x == 0) out[0] = v / (float)(T * B);
}

extern "C" void kernel_launch(void* const* d_in, const int* in_sizes, int n_in,
                              void* d_out, int out_size, void* d_ws, size_t ws_size,
                              hipStream_t stream)
{
    const float* q       = (const float*)d_in[0];
    const float* tq_traj = (const float*)d_in[1];
    const float* tq_curr = (const float*)d_in[2];
    const float* rewards = (const float*)d_in[3];
    const float* olp     = (const float*)d_in[4];
    const float* tlp     = (const float*)d_in[5];

    float* partials = (float*)d_ws;   // NBLK floats
    float* out      = (float*)d_out;

    retrace_main<<<NBLK, NSEG * CPB, 0, stream>>>(
        q, tq_traj, tq_curr, rewards, olp, tlp, partials);
    retrace_final<<<1, 64, 0, stream>>>(partials, out);
}